// Round 5
// baseline (1056.345 us; speedup 1.0000x reference)
//
#include <hip/hip_runtime.h>

#define N_NODES 500000
#define N_EDGES 5000000
#define N_GRAPHS 5000
#define FEAT 7
#define STATE 16
#define NB_SCAN 1954  // ceil(N_NODES/256)

// ---------------- zero an int buffer ----------------------------------------
__global__ __launch_bounds__(256) void k_zero(int* __restrict__ p, int n) {
    int i = blockIdx.x * 256 + threadIdx.x;
    if (i < n) p[i] = 0;
}

// ---------------- input layer: state = relu(x @ in_W + in_b) ----------------
__global__ __launch_bounds__(256) void k_input(const float* __restrict__ x,
                                               const float* __restrict__ W,
                                               const float* __restrict__ b,
                                               float* __restrict__ state) {
    int i = blockIdx.x * 256 + threadIdx.x;
    if (i >= N_NODES) return;
    float xi[FEAT];
#pragma unroll
    for (int f = 0; f < FEAT; ++f) xi[f] = x[(size_t)i * FEAT + f];
    float o[STATE];
#pragma unroll
    for (int s = 0; s < STATE; ++s) {
        float acc = b[s];
#pragma unroll
        for (int f = 0; f < FEAT; ++f) acc = fmaf(xi[f], W[f * STATE + s], acc);
        o[s] = fmaxf(acc, 0.f);
    }
    float4* dst = reinterpret_cast<float4*>(state + (size_t)i * STATE);
#pragma unroll
    for (int q = 0; q < 4; ++q)
        dst[q] = make_float4(o[4 * q], o[4 * q + 1], o[4 * q + 2], o[4 * q + 3]);
}

// ---------------- CSR build: histogram with position capture ----------------
__global__ __launch_bounds__(256) void k_hist(const int* __restrict__ ei,
                                              int* __restrict__ deg,
                                              int* __restrict__ pos) {
    int e = blockIdx.x * 256 + threadIdx.x;
    if (e >= N_EDGES) return;
    int d = ei[N_EDGES + e];
    pos[e] = atomicAdd(&deg[d], 1);
}

// ---------------- 3-kernel exclusive scan over deg[] ------------------------
__global__ __launch_bounds__(256) void k_scan1(const int* __restrict__ deg,
                                               int* __restrict__ offs,
                                               int* __restrict__ bsum) {
    __shared__ int wsum[4];
    int b = blockIdx.x, t = threadIdx.x, lane = t & 63, w = t >> 6;
    int i = b * 256 + t;
    int v = (i < N_NODES) ? deg[i] : 0;
    int s = v;
#pragma unroll
    for (int off = 1; off < 64; off <<= 1) {
        int o = __shfl_up(s, off);
        if (lane >= off) s += o;
    }
    if (lane == 63) wsum[w] = s;
    __syncthreads();
    int wofs = 0;
#pragma unroll
    for (int k = 0; k < 4; ++k)
        if (k < w) wofs += wsum[k];
    if (i < N_NODES) offs[i] = wofs + s - v;  // block-local exclusive
    if (t == 255) bsum[b] = wofs + s;         // block total
}

__global__ __launch_bounds__(256) void k_scan2(int* __restrict__ bsum) {
    __shared__ int wsum[4];
    __shared__ int carry_s;
    int t = threadIdx.x, lane = t & 63, w = t >> 6;
    if (t == 0) carry_s = 0;
    __syncthreads();
    for (int base = 0; base < NB_SCAN; base += 256) {
        int i = base + t;
        int v = (i < NB_SCAN) ? bsum[i] : 0;
        int s = v;
#pragma unroll
        for (int off = 1; off < 64; off <<= 1) {
            int o = __shfl_up(s, off);
            if (lane >= off) s += o;
        }
        if (lane == 63) wsum[w] = s;
        __syncthreads();
        int wofs = 0;
#pragma unroll
        for (int k = 0; k < 4; ++k)
            if (k < w) wofs += wsum[k];
        int incl = wofs + s;
        int carry = carry_s;
        if (i < NB_SCAN) bsum[i] = carry + incl - v;  // exclusive across chunks
        __syncthreads();
        if (t == 255) carry_s = carry + incl;
        __syncthreads();
    }
}

__global__ __launch_bounds__(256) void k_scan3(int* __restrict__ offs,
                                               const int* __restrict__ bsum) {
    int i = blockIdx.x * 256 + threadIdx.x;
    if (i < N_NODES) offs[i] += bsum[blockIdx.x];
    if (i == 0) offs[N_NODES] = N_EDGES;  // backfill sentinel
}

// ---------------- scatter edge srcs into CSR slots --------------------------
__global__ __launch_bounds__(256) void k_scatter(const int* __restrict__ ei,
                                                 const int* __restrict__ offs,
                                                 const int* __restrict__ pos,
                                                 int* __restrict__ srcs) {
    int e = blockIdx.x * 256 + threadIdx.x;
    if (e >= N_EDGES) return;
    int d = ei[N_EDGES + e];
    srcs[offs[d] + pos[e]] = ei[e];
}

// ------- degree counting-sort: pass 1 (LDS hist + block-base capture) -------
__global__ __launch_bounds__(256) void k_dhist(const int* __restrict__ deg,
                                               int* __restrict__ gcnt,
                                               int* __restrict__ bb) {
    __shared__ int bins[64];
    int t = threadIdx.x, blk = blockIdx.x;
    if (t < 64) bins[t] = 0;
    __syncthreads();
    int i = blk * 256 + t;
    if (i < N_NODES) {
        int b = min(deg[i], 63);
        atomicAdd(&bins[b], 1);
    }
    __syncthreads();
    if (t < 64) {
        int c = bins[t];
        int base = atomicAdd(&gcnt[t], c);  // per-bin global cursor
        bb[blk * 64 + t] = base;
    }
}

// ------- degree counting-sort: scan gcnt[64] exclusive (1 wave) -------------
__global__ __launch_bounds__(64) void k_dscan(int* __restrict__ gcnt) {
    int t = threadIdx.x;
    int v = gcnt[t];
    int s = v;
#pragma unroll
    for (int off = 1; off < 64; off <<= 1) {
        int o = __shfl_up(s, off);
        if (t >= off) s += o;
    }
    gcnt[t] = s - v;  // exclusive
}

// ------- degree counting-sort: pass 2 (place node ids) ----------------------
__global__ __launch_bounds__(256) void k_dscatter(const int* __restrict__ deg,
                                                  const int* __restrict__ gcnt,
                                                  const int* __restrict__ bb,
                                                  int* __restrict__ perm) {
    __shared__ int cur[64];
    int t = threadIdx.x, blk = blockIdx.x;
    if (t < 64) cur[t] = 0;
    __syncthreads();
    int i = blk * 256 + t;
    if (i < N_NODES) {
        int b = min(deg[i], 63);
        int r = atomicAdd(&cur[b], 1);
        perm[gcnt[b] + bb[blk * 64 + b] + r] = i;
    }
}

// ------- message = relu(state @ W + b) --------------------------------------
__global__ __launch_bounds__(256) void k_message(const float* __restrict__ state,
                                                 const float* __restrict__ W,
                                                 const float* __restrict__ b,
                                                 float* __restrict__ message) {
    int i = blockIdx.x * 256 + threadIdx.x;
    if (i >= N_NODES) return;
    const float4* sp = reinterpret_cast<const float4*>(state + (size_t)i * STATE);
    float4 v0 = sp[0], v1 = sp[1], v2 = sp[2], v3 = sp[3];
    float st[STATE] = {v0.x, v0.y, v0.z, v0.w, v1.x, v1.y, v1.z, v1.w,
                       v2.x, v2.y, v2.z, v2.w, v3.x, v3.y, v3.z, v3.w};
    float o[STATE];
#pragma unroll
    for (int s = 0; s < STATE; ++s) {
        float acc = b[s];
#pragma unroll
        for (int k = 0; k < STATE; ++k) acc = fmaf(st[k], W[k * STATE + s], acc);
        o[s] = fmaxf(acc, 0.f);
    }
    float4* mp = reinterpret_cast<float4*>(message + (size_t)i * STATE);
#pragma unroll
    for (int q = 0; q < 4; ++q)
        mp[q] = make_float4(o[4 * q], o[4 * q + 1], o[4 * q + 2], o[4 * q + 3]);
}

// ------- atomic-free gather + fused update, degree-sorted order -------------
__global__ __launch_bounds__(256) void k_gather_update(
    const float* __restrict__ message, const int* __restrict__ offs,
    const int* __restrict__ perm, const int* __restrict__ srcs,
    const float* __restrict__ W, const float* __restrict__ b,
    float* __restrict__ state) {
    int t = blockIdx.x * 256 + threadIdx.x;
    if (t >= N_NODES) return;
    int i = perm[t];  // nodes in degree order -> uniform trip counts per wave
    int start = offs[i], end = offs[i + 1];
    float acc[STATE];
#pragma unroll
    for (int s = 0; s < STATE; ++s) acc[s] = 0.f;
#pragma unroll 4
    for (int j = start; j < end; ++j) {
        int s = srcs[j];
        const float4* mp = reinterpret_cast<const float4*>(message + (size_t)s * STATE);
        float4 m0 = mp[0], m1 = mp[1], m2 = mp[2], m3 = mp[3];
        acc[0] += m0.x;  acc[1] += m0.y;  acc[2] += m0.z;  acc[3] += m0.w;
        acc[4] += m1.x;  acc[5] += m1.y;  acc[6] += m1.z;  acc[7] += m1.w;
        acc[8] += m2.x;  acc[9] += m2.y;  acc[10] += m2.z; acc[11] += m2.w;
        acc[12] += m3.x; acc[13] += m3.y; acc[14] += m3.z; acc[15] += m3.w;
    }
    float* sp = state + (size_t)i * STATE;
    float4* spv = reinterpret_cast<float4*>(sp);
    float4 s0 = spv[0], s1 = spv[1], s2 = spv[2], s3 = spv[3];
    float st[STATE] = {s0.x, s0.y, s0.z, s0.w, s1.x, s1.y, s1.z, s1.w,
                       s2.x, s2.y, s2.z, s2.w, s3.x, s3.y, s3.z, s3.w};
#pragma unroll
    for (int s = 0; s < STATE; ++s) {
        float a = b[s];
#pragma unroll
        for (int k = 0; k < STATE; ++k) a = fmaf(acc[k], W[k * STATE + s], a);
        st[s] += fmaxf(a, 0.f);
    }
#pragma unroll
    for (int q = 0; q < 4; ++q)
        spv[q] = make_float4(st[4 * q], st[4 * q + 1], st[4 * q + 2], st[4 * q + 3]);
}

// ------------- out[g] = out_b -----------------------------------------------
__global__ __launch_bounds__(256) void k_out_init(const float* __restrict__ out_b,
                                                  float* __restrict__ out) {
    int g = blockIdx.x * 256 + threadIdx.x;
    if (g < N_GRAPHS) out[g] = out_b[0];
}

// ------------- out[batch[i]] += dot(state[i], out_W) ------------------------
__global__ __launch_bounds__(256) void k_reduce(const float* __restrict__ state,
                                                const int* __restrict__ batch,
                                                const float* __restrict__ out_W,
                                                float* __restrict__ out) {
    int i = blockIdx.x * 256 + threadIdx.x;
    int lane = threadIdx.x & 63;
    bool valid = (i < N_NODES);
    float v = 0.f;
    int bg = -1;
    if (valid) {
        bg = batch[i];
        const float4* sp = reinterpret_cast<const float4*>(state + (size_t)i * STATE);
        float4 s0 = sp[0], s1 = sp[1], s2 = sp[2], s3 = sp[3];
        float st[STATE] = {s0.x, s0.y, s0.z, s0.w, s1.x, s1.y, s1.z, s1.w,
                           s2.x, s2.y, s2.z, s2.w, s3.x, s3.y, s3.z, s3.w};
        float acc = 0.f;
#pragma unroll
        for (int k = 0; k < STATE; ++k) acc = fmaf(st[k], out_W[k], acc);
        v = acc;
    }
#pragma unroll
    for (int off = 1; off < 64; off <<= 1) {
        float ov = __shfl_up(v, off);
        int ob = __shfl_up(bg, off);
        if (lane >= off && ob == bg) v += ov;
    }
    int nb = __shfl_down(bg, 1);
    if (valid && (lane == 63 || nb != bg)) unsafeAtomicAdd(&out[bg], v);
}

extern "C" void kernel_launch(void* const* d_in, const int* in_sizes, int n_in,
                              void* d_out, int out_size, void* d_ws, size_t ws_size,
                              hipStream_t stream) {
    const float* x     = (const float*)d_in[0];
    const int*   ei    = (const int*)d_in[1];
    const int*   batch = (const int*)d_in[2];
    const float* in_W  = (const float*)d_in[3];
    const float* in_b  = (const float*)d_in[4];
    const float* msg_W = (const float*)d_in[5];
    const float* msg_b = (const float*)d_in[6];
    const float* upd_W = (const float*)d_in[7];
    const float* upd_b = (const float*)d_in[8];
    const float* out_W = (const float*)d_in[9];
    const float* out_b = (const float*)d_in[10];
    float* out = (float*)d_out;

    // workspace layout (~90 MB):
    float* state   = (float*)d_ws;                               // 32 MB
    float* message = state + (size_t)N_NODES * STATE;            // 32 MB
    int*   srcs    = (int*)(message + (size_t)N_NODES * STATE);  // 20 MB
    int*   deg     = srcs + N_EDGES;                             // 2 MB
    int*   offs    = deg + N_NODES;                              // 2 MB (+1)
    int*   bsum    = offs + N_NODES + 1;                         // 8 KB
    int*   gcnt    = bsum + 2048;                                // 256 B
    int*   perm    = gcnt + 64;                                  // 2 MB
    // overlap into message buffer (only live during CSR build, pre-k_message):
    int*   pos     = (int*)message;                // 5M ints
    int*   bb      = (int*)message + N_EDGES;      // 1954*64 ints

    const int nbN = (N_NODES + 255) / 256;
    const int nbE = (N_EDGES + 255) / 256;
    const int nbG = (N_GRAPHS + 255) / 256;

    // ---- CSR build (by dst) ----
    k_zero<<<(N_NODES + 64 + 255) / 256, 256, 0, stream>>>(deg, N_NODES);
    k_zero<<<1, 256, 0, stream>>>(gcnt, 64);
    k_hist<<<nbE, 256, 0, stream>>>(ei, deg, pos);
    k_scan1<<<NB_SCAN, 256, 0, stream>>>(deg, offs, bsum);
    k_scan2<<<1, 256, 0, stream>>>(bsum);
    k_scan3<<<NB_SCAN, 256, 0, stream>>>(offs, bsum);
    k_scatter<<<nbE, 256, 0, stream>>>(ei, offs, pos, srcs);

    // ---- degree counting-sort -> perm ----
    k_dhist<<<NB_SCAN, 256, 0, stream>>>(deg, gcnt, bb);
    k_dscan<<<1, 64, 0, stream>>>(gcnt);
    k_dscatter<<<NB_SCAN, 256, 0, stream>>>(deg, gcnt, bb, perm);

    // ---- GNN ----
    k_input<<<nbN, 256, 0, stream>>>(x, in_W, in_b, state);
    for (int r = 0; r < 4; ++r) {
        k_message<<<nbN, 256, 0, stream>>>(state, msg_W + r * STATE * STATE,
                                           msg_b + r * STATE, message);
        k_gather_update<<<nbN, 256, 0, stream>>>(message, offs, perm, srcs,
                                                 upd_W + r * STATE * STATE,
                                                 upd_b + r * STATE, state);
    }
    k_out_init<<<nbG, 256, 0, stream>>>(out_b, out);
    k_reduce<<<nbN, 256, 0, stream>>>(state, batch, out_W, out);
}

// Round 6
// 813.154 us; speedup vs baseline: 1.2991x; 1.2991x over previous
//
#include <hip/hip_runtime.h>

#define N_NODES 500000
#define N_EDGES 5000000
#define N_GRAPHS 5000
#define FEAT 7
#define STATE 16
#define NBUCK ((N_NODES + 1023) >> 10)   // 489 buckets of 1024 nodes
#define NBLK1 512
#define EPB ((N_EDGES + NBLK1 - 1) / NBLK1)  // 9766 edges per pass-1 block

// ---------------- zero an int buffer ----------------------------------------
__global__ __launch_bounds__(256) void k_zero(int* __restrict__ p, int n) {
    int i = blockIdx.x * 256 + threadIdx.x;
    if (i < n) p[i] = 0;
}

// ---------------- input layer: state = relu(x @ in_W + in_b) ----------------
__global__ __launch_bounds__(256) void k_input(const float* __restrict__ x,
                                               const float* __restrict__ W,
                                               const float* __restrict__ b,
                                               float* __restrict__ state) {
    int i = blockIdx.x * 256 + threadIdx.x;
    if (i >= N_NODES) return;
    float xi[FEAT];
#pragma unroll
    for (int f = 0; f < FEAT; ++f) xi[f] = x[(size_t)i * FEAT + f];
    float o[STATE];
#pragma unroll
    for (int s = 0; s < STATE; ++s) {
        float acc = b[s];
#pragma unroll
        for (int f = 0; f < FEAT; ++f) acc = fmaf(xi[f], W[f * STATE + s], acc);
        o[s] = fmaxf(acc, 0.f);
    }
    float4* dst = reinterpret_cast<float4*>(state + (size_t)i * STATE);
#pragma unroll
    for (int q = 0; q < 4; ++q)
        dst[q] = make_float4(o[4 * q], o[4 * q + 1], o[4 * q + 2], o[4 * q + 3]);
}

// ---- CSR pass 1a: per-block bucket histogram + global base capture ---------
__global__ __launch_bounds__(256) void k_bhist(const int* __restrict__ ei,
                                               int* __restrict__ bcnt,
                                               int* __restrict__ bb) {
    __shared__ int bins[NBUCK];
    int t = threadIdx.x, blk = blockIdx.x;
    for (int k = t; k < NBUCK; k += 256) bins[k] = 0;
    __syncthreads();
    int e0 = blk * EPB, e1 = min(e0 + EPB, N_EDGES);
    for (int e = e0 + t; e < e1; e += 256) {
        int d = ei[N_EDGES + e];
        atomicAdd(&bins[d >> 10], 1);
    }
    __syncthreads();
    for (int k = t; k < NBUCK; k += 256)
        bb[blk * NBUCK + k] = atomicAdd(&bcnt[k], bins[k]);
}

// ---- CSR pass 1b: tiny exclusive scan of bucket counts ---------------------
__global__ __launch_bounds__(256) void k_bscan(const int* __restrict__ bcnt,
                                               int* __restrict__ boffs,
                                               int* __restrict__ offs) {
    __shared__ int sc[NBUCK];
    int t = threadIdx.x;
    for (int k = t; k < NBUCK; k += 256) sc[k] = bcnt[k];
    __syncthreads();
    if (t == 0) {
        int run = 0;
        for (int k = 0; k < NBUCK; ++k) { int v = sc[k]; sc[k] = run; run += v; }
    }
    __syncthreads();
    for (int k = t; k < NBUCK; k += 256) boffs[k] = sc[k];
    if (t == 0) { boffs[NBUCK] = N_EDGES; offs[N_NODES] = N_EDGES; }
}

// ---- CSR pass 1c: partition edges into bucket-contiguous packed storage ----
// pack = src | (dst&1023)<<19   (valid: N_NODES < 2^19)
__global__ __launch_bounds__(256) void k_bscatter(const int* __restrict__ ei,
                                                  const int* __restrict__ boffs,
                                                  const int* __restrict__ bb,
                                                  int* __restrict__ ebuf) {
    __shared__ int cur[NBUCK];
    int t = threadIdx.x, blk = blockIdx.x;
    for (int k = t; k < NBUCK; k += 256) cur[k] = 0;
    __syncthreads();
    int e0 = blk * EPB, e1 = min(e0 + EPB, N_EDGES);
    for (int e = e0 + t; e < e1; e += 256) {
        int s = ei[e];
        int d = ei[N_EDGES + e];
        int bin = d >> 10;
        int r = atomicAdd(&cur[bin], 1);
        ebuf[boffs[bin] + bb[blk * NBUCK + bin] + r] = s | ((d & 1023) << 19);
    }
}

// ---- CSR pass 2: per-bucket CSR build fully in LDS (no global atomics) -----
__global__ __launch_bounds__(256) void k_bcsr(const int* __restrict__ ebuf,
                                              const int* __restrict__ boffs,
                                              int* __restrict__ offs,
                                              int* __restrict__ srcs) {
    __shared__ int hist[1024];
    __shared__ int cur[1024];
    __shared__ int wsum[4];
    int t = threadIdx.x, blk = blockIdx.x;
    int nb = blk << 10;
    int nn = min(1024, N_NODES - nb);
    for (int k = t; k < 1024; k += 256) hist[k] = 0;
    __syncthreads();
    int e0 = boffs[blk], e1 = boffs[blk + 1];
    for (int e = e0 + t; e < e1; e += 256)
        atomicAdd(&hist[(ebuf[e] >> 19) & 1023], 1);
    __syncthreads();
    // block-exclusive scan of hist[0..1024), 4 elems/thread
    int v0 = hist[4 * t], v1 = hist[4 * t + 1], v2 = hist[4 * t + 2], v3 = hist[4 * t + 3];
    int tsum = v0 + v1 + v2 + v3;
    int lane = t & 63, w = t >> 6;
    int s = tsum;
#pragma unroll
    for (int off = 1; off < 64; off <<= 1) {
        int o = __shfl_up(s, off);
        if (lane >= off) s += o;
    }
    if (lane == 63) wsum[w] = s;
    __syncthreads();
    int wofs = 0;
#pragma unroll
    for (int k = 0; k < 4; ++k)
        if (k < w) wofs += wsum[k];
    int ex = wofs + s - tsum;
    cur[4 * t] = ex;
    cur[4 * t + 1] = ex + v0;
    cur[4 * t + 2] = ex + v0 + v1;
    cur[4 * t + 3] = ex + v0 + v1 + v2;
    __syncthreads();
    for (int k = t; k < nn; k += 256) offs[nb + k] = e0 + cur[k];
    __syncthreads();  // offs reads of cur[] must precede cursor atomics
    for (int e = e0 + t; e < e1; e += 256) {
        int p = ebuf[e];
        int r = atomicAdd(&cur[(p >> 19) & 1023], 1);
        srcs[e0 + r] = p & 0x7FFFF;
    }
}

// ------- message = relu(state @ W + b) --------------------------------------
__global__ __launch_bounds__(256) void k_message(const float* __restrict__ state,
                                                 const float* __restrict__ W,
                                                 const float* __restrict__ b,
                                                 float* __restrict__ message) {
    int i = blockIdx.x * 256 + threadIdx.x;
    if (i >= N_NODES) return;
    const float4* sp = reinterpret_cast<const float4*>(state + (size_t)i * STATE);
    float4 v0 = sp[0], v1 = sp[1], v2 = sp[2], v3 = sp[3];
    float st[STATE] = {v0.x, v0.y, v0.z, v0.w, v1.x, v1.y, v1.z, v1.w,
                       v2.x, v2.y, v2.z, v2.w, v3.x, v3.y, v3.z, v3.w};
    float o[STATE];
#pragma unroll
    for (int s = 0; s < STATE; ++s) {
        float acc = b[s];
#pragma unroll
        for (int k = 0; k < STATE; ++k) acc = fmaf(st[k], W[k * STATE + s], acc);
        o[s] = fmaxf(acc, 0.f);
    }
    float4* mp = reinterpret_cast<float4*>(message + (size_t)i * STATE);
#pragma unroll
    for (int q = 0; q < 4; ++q)
        mp[q] = make_float4(o[4 * q], o[4 * q + 1], o[4 * q + 2], o[4 * q + 3]);
}

// ------- atomic-free gather + fused update ----------------------------------
__global__ __launch_bounds__(256) void k_gather_update(
    const float* __restrict__ message, const int* __restrict__ offs,
    const int* __restrict__ srcs, const float* __restrict__ W,
    const float* __restrict__ b, float* __restrict__ state) {
    int i = blockIdx.x * 256 + threadIdx.x;
    if (i >= N_NODES) return;
    int start = offs[i], end = offs[i + 1];
    float acc[STATE];
#pragma unroll
    for (int s = 0; s < STATE; ++s) acc[s] = 0.f;
    for (int j = start; j < end; ++j) {
        int s = srcs[j];
        const float4* mp = reinterpret_cast<const float4*>(message + (size_t)s * STATE);
        float4 m0 = mp[0], m1 = mp[1], m2 = mp[2], m3 = mp[3];
        acc[0] += m0.x;  acc[1] += m0.y;  acc[2] += m0.z;  acc[3] += m0.w;
        acc[4] += m1.x;  acc[5] += m1.y;  acc[6] += m1.z;  acc[7] += m1.w;
        acc[8] += m2.x;  acc[9] += m2.y;  acc[10] += m2.z; acc[11] += m2.w;
        acc[12] += m3.x; acc[13] += m3.y; acc[14] += m3.z; acc[15] += m3.w;
    }
    float* sp = state + (size_t)i * STATE;
    float4* spv = reinterpret_cast<float4*>(sp);
    float4 s0 = spv[0], s1 = spv[1], s2 = spv[2], s3 = spv[3];
    float st[STATE] = {s0.x, s0.y, s0.z, s0.w, s1.x, s1.y, s1.z, s1.w,
                       s2.x, s2.y, s2.z, s2.w, s3.x, s3.y, s3.z, s3.w};
#pragma unroll
    for (int s = 0; s < STATE; ++s) {
        float a = b[s];
#pragma unroll
        for (int k = 0; k < STATE; ++k) a = fmaf(acc[k], W[k * STATE + s], a);
        st[s] += fmaxf(a, 0.f);
    }
#pragma unroll
    for (int q = 0; q < 4; ++q)
        spv[q] = make_float4(st[4 * q], st[4 * q + 1], st[4 * q + 2], st[4 * q + 3]);
}

// ------------- out[g] = out_b -----------------------------------------------
__global__ __launch_bounds__(256) void k_out_init(const float* __restrict__ out_b,
                                                  float* __restrict__ out) {
    int g = blockIdx.x * 256 + threadIdx.x;
    if (g < N_GRAPHS) out[g] = out_b[0];
}

// ------------- out[batch[i]] += dot(state[i], out_W) ------------------------
__global__ __launch_bounds__(256) void k_reduce(const float* __restrict__ state,
                                                const int* __restrict__ batch,
                                                const float* __restrict__ out_W,
                                                float* __restrict__ out) {
    int i = blockIdx.x * 256 + threadIdx.x;
    int lane = threadIdx.x & 63;
    bool valid = (i < N_NODES);
    float v = 0.f;
    int bg = -1;
    if (valid) {
        bg = batch[i];
        const float4* sp = reinterpret_cast<const float4*>(state + (size_t)i * STATE);
        float4 s0 = sp[0], s1 = sp[1], s2 = sp[2], s3 = sp[3];
        float st[STATE] = {s0.x, s0.y, s0.z, s0.w, s1.x, s1.y, s1.z, s1.w,
                           s2.x, s2.y, s2.z, s2.w, s3.x, s3.y, s3.z, s3.w};
        float acc = 0.f;
#pragma unroll
        for (int k = 0; k < STATE; ++k) acc = fmaf(st[k], out_W[k], acc);
        v = acc;
    }
#pragma unroll
    for (int off = 1; off < 64; off <<= 1) {
        float ov = __shfl_up(v, off);
        int ob = __shfl_up(bg, off);
        if (lane >= off && ob == bg) v += ov;
    }
    int nb = __shfl_down(bg, 1);
    if (valid && (lane == 63 || nb != bg)) unsafeAtomicAdd(&out[bg], v);
}

extern "C" void kernel_launch(void* const* d_in, const int* in_sizes, int n_in,
                              void* d_out, int out_size, void* d_ws, size_t ws_size,
                              hipStream_t stream) {
    const float* x     = (const float*)d_in[0];
    const int*   ei    = (const int*)d_in[1];
    const int*   batch = (const int*)d_in[2];
    const float* in_W  = (const float*)d_in[3];
    const float* in_b  = (const float*)d_in[4];
    const float* msg_W = (const float*)d_in[5];
    const float* msg_b = (const float*)d_in[6];
    const float* upd_W = (const float*)d_in[7];
    const float* upd_b = (const float*)d_in[8];
    const float* out_W = (const float*)d_in[9];
    const float* out_b = (const float*)d_in[10];
    float* out = (float*)d_out;

    // workspace layout (~88 MB):
    float* state   = (float*)d_ws;                               // 32 MB
    float* message = state + (size_t)N_NODES * STATE;            // 32 MB
    int*   srcs    = (int*)(message + (size_t)N_NODES * STATE);  // 20 MB
    int*   offs    = srcs + N_EDGES;                             // 2 MB (+1)
    int*   bcnt    = offs + N_NODES + 1;                         // 489
    int*   boffs   = bcnt + NBUCK;                               // 490
    int*   bb      = boffs + NBUCK + 1;                          // 1 MB
    // ebuf (20 MB) overlaps state: only live during CSR build, before k_input
    int*   ebuf    = (int*)d_ws;

    const int nbN = (N_NODES + 255) / 256;
    const int nbG = (N_GRAPHS + 255) / 256;

    // ---- CSR build by dst (bucketed, near-atomic-free) ----
    k_zero<<<(NBUCK + 255) / 256, 256, 0, stream>>>(bcnt, NBUCK);
    k_bhist<<<NBLK1, 256, 0, stream>>>(ei, bcnt, bb);
    k_bscan<<<1, 256, 0, stream>>>(bcnt, boffs, offs);
    k_bscatter<<<NBLK1, 256, 0, stream>>>(ei, boffs, bb, ebuf);
    k_bcsr<<<NBUCK, 256, 0, stream>>>(ebuf, boffs, offs, srcs);

    // ---- GNN ----
    k_input<<<nbN, 256, 0, stream>>>(x, in_W, in_b, state);
    for (int r = 0; r < 4; ++r) {
        k_message<<<nbN, 256, 0, stream>>>(state, msg_W + r * STATE * STATE,
                                           msg_b + r * STATE, message);
        k_gather_update<<<nbN, 256, 0, stream>>>(message, offs, srcs,
                                                 upd_W + r * STATE * STATE,
                                                 upd_b + r * STATE, state);
    }
    k_out_init<<<nbG, 256, 0, stream>>>(out_b, out);
    k_reduce<<<nbN, 256, 0, stream>>>(state, batch, out_W, out);
}